// Round 9
// baseline (34.718 us; speedup 1.0000x reference)
//
#include <hip/hip_runtime.h>

#define B_ 4
#define T_ 8
#define N_ 256
#define F_ 16
#define D_ 64
#define NP (D_/2)       // 32 pairs per row
#define CHUNK 8
#define NCH (N_/CHUNK)  // 32 -> main grid = 1024 blocks = 4/CU exactly

#define SC 2.8853900817779268f        // 2*log2(e): exp2(SC*x) = e^{2x}
#define LOG2E 1.4426950408889634f

typedef __attribute__((ext_vector_type(16))) float f32x16;

__device__ __forceinline__ float fast_exp2(float x) { return __builtin_amdgcn_exp2f(x); }
__device__ __forceinline__ float fast_rcp(float x)  { return __builtin_amdgcn_rcpf(x); }

// ---------------- prologue ----------------
// q-rows -> StreamQ[row][pr quads] = (eqa, eqb, 2*L2E*w0, 2*L2E*w1)
// k-rows -> EkT[bt][d][m] (transposed, coalesced main loads)
// row 0 wave also writes hdr[0] = LOG2E * sum(wt)
__global__ __launch_bounds__(256)
void tattn_proj_kernel(const float* __restrict__ query,
                       const float* __restrict__ keys,
                       const float* __restrict__ Wq, const float* __restrict__ bq,
                       const float* __restrict__ Wk, const float* __restrict__ bk,
                       const float* __restrict__ wt,
                       float* __restrict__ StreamQ, float* __restrict__ EkT,
                       float* __restrict__ hdr)
{
    const int tid = threadIdx.x;
    const int row = blockIdx.x * 4 + (tid >> 6);   // 4 rows (waves) per block
    const int j   = tid & 63;
    const int NQ  = B_ * N_;

    if (row < NQ) {                                // wave-uniform branch
        const float* in = query + (size_t)row * F_;
        float acc = bq[j];
        #pragma unroll
        for (int f = 0; f < F_; ++f) acc = fmaf(in[f], Wq[f * D_ + j], acc);
        float eq = fast_exp2(acc * SC);
        float* qs = StreamQ + (size_t)row * (4 * NP);
        const int pr = j >> 1;
        const float w2l = 2.0f * LOG2E * wt[j];
        if ((j & 1) == 0) { qs[4*pr + 0] = eq; qs[4*pr + 2] = w2l; }
        else              { qs[4*pr + 1] = eq; qs[4*pr + 3] = w2l; }
        if (row == 0) {                            // Wsum header (once)
            float w = wt[j];
            #pragma unroll
            for (int off = 32; off >= 1; off >>= 1) w += __shfl_xor(w, off);
            if (j == 0) hdr[0] = w * LOG2E;
        }
    } else {
        const int r  = row - NQ;                   // r = bt*N + n
        const int bt = r >> 8, n = r & (N_ - 1);
        const float* in = keys + (size_t)r * F_;
        float acc = bk[j];
        #pragma unroll
        for (int f = 0; f < F_; ++f) acc = fmaf(in[f], Wk[f * D_ + j], acc);
        EkT[((size_t)bt * D_ + j) * N_ + n] = fast_exp2(acc * SC);
    }
}

// ---------------- main ----------------
// scoreL(n,m) = WsumL - sum_pairs (W0*qA + W1*pA) * rcp(pA*qA), pA=1+eqa*ek0, qA=1+eqb*ek1
// Stream quads arrive via rotating 2-deep s_load_dwordx16 pipeline (drain -> issue-next -> compute).
// Hot loop: zero LDS reads, zero VMEM. VGPR target ~92 -> 4 waves/SIMD, zero tail.
__global__ __launch_bounds__(256, 4)
void tattn_main_kernel(const float* __restrict__ StreamQ,
                       const float* __restrict__ EkT,
                       const float* __restrict__ hdr,
                       float* __restrict__ out)
{
    __shared__ float pbuf[CHUNK][N_];   // 8 KB
    __shared__ float totL[CHUNK];

    const int tid = threadIdx.x;
    const int bid = blockIdx.x;
    const int ch  = bid % NCH;
    const int t   = (bid / NCH) % T_;
    const int b   = bid / (NCH * T_);
    const int n0  = ch * CHUNK;
    const int bt  = b * T_ + t;

    // Ek column for key m=tid: 64 coalesced wave loads
    float kreg[D_];
    {
        const float* kp = EkT + (size_t)bt * D_ * N_ + tid;
        #pragma unroll
        for (int d = 0; d < D_; ++d) kreg[d] = kp[(size_t)d * N_];
    }

    const float WsumL = *hdr;                      // uniform broadcast load
    const float* srow = StreamQ + ((size_t)(b * N_ + n0)) * (4 * NP);  // 4 KB window

    f32x16 cA0, cA1, cB0, cB1;
    float ac0 = 0.f, ac1 = 0.f, ac2 = 0.f, ac3 = 0.f;

    // prologue: issue batch 0 into A
    asm volatile("s_load_dwordx16 %0, %2, 0x0\n\t"
                 "s_load_dwordx16 %1, %2, 0x40"
                 : "=&s"(cA0), "=&s"(cA1) : "s"(srow));

#define STEP(C0, C1, X0, X1, KK)                                              \
    {                                                                         \
        asm volatile("s_waitcnt lgkmcnt(0)" : "+s"(C0), "+s"(C1));            \
        if ((KK) + 1 < 32) {                                                  \
            asm volatile("s_load_dwordx16 %0, %2, 0x0\n\t"                    \
                         "s_load_dwordx16 %1, %2, 0x40"                       \
                         : "=&s"(X0), "=&s"(X1)                               \
                         : "s"(srow + ((KK) + 1) * 32));                      \
        }                                                                     \
        __builtin_amdgcn_sched_barrier(0);                                    \
        if (((KK) & 3) == 0) { ac0 = 0.f; ac1 = 0.f; ac2 = 0.f; ac3 = 0.f; }  \
        _Pragma("unroll")                                                     \
        for (int i = 0; i < 8; ++i) {                                         \
            const int pr = ((KK) & 3) * 8 + i;                                \
            float ea = (i < 4) ? C0[4*i+0] : C1[4*(i-4)+0];                   \
            float eb = (i < 4) ? C0[4*i+1] : C1[4*(i-4)+1];                   \
            float W0 = (i < 4) ? C0[4*i+2] : C1[4*(i-4)+2];                   \
            float W1 = (i < 4) ? C0[4*i+3] : C1[4*(i-4)+3];                   \
            float pA = fmaf(ea, kreg[2*pr+0], 1.0f);                          \
            float qA = fmaf(eb, kreg[2*pr+1], 1.0f);                          \
            float nA = fmaf(W0, qA, W1 * pA);                                 \
            float r  = fast_rcp(pA * qA);                                     \
            if      (i == 0 || i == 4) ac0 = fmaf(nA, r, ac0);                \
            else if (i == 1 || i == 5) ac1 = fmaf(nA, r, ac1);                \
            else if (i == 2 || i == 6) ac2 = fmaf(nA, r, ac2);                \
            else                       ac3 = fmaf(nA, r, ac3);                \
        }                                                                     \
        if (((KK) & 3) == 3)                                                  \
            pbuf[(KK) >> 2][tid] =                                            \
                fast_exp2(WsumL - ((ac0 + ac1) + (ac2 + ac3)));               \
    }

#define ROW(R)                                  \
    STEP(cA0, cA1, cB0, cB1, (R)*4 + 0)         \
    STEP(cB0, cB1, cA0, cA1, (R)*4 + 1)         \
    STEP(cA0, cA1, cB0, cB1, (R)*4 + 2)         \
    STEP(cB0, cB1, cA0, cA1, (R)*4 + 3)

    ROW(0) ROW(1) ROW(2) ROW(3) ROW(4) ROW(5) ROW(6) ROW(7)
#undef ROW
#undef STEP

    __syncthreads();

    // per-row totals: wave w reduces rows 2w, 2w+1
    const int lane = tid & 63;
    const int wid  = tid >> 6;
    #pragma unroll
    for (int rr = 0; rr < 2; ++rr) {
        const int row = wid * 2 + rr;
        float4 v = *reinterpret_cast<const float4*>(&pbuf[row][lane * 4]);
        float s = (v.x + v.y) + (v.z + v.w);
        #pragma unroll
        for (int off = 32; off >= 1; off >>= 1) s += __shfl_xor(s, off);
        if (lane == 0) totL[row] = s;
    }
    __syncthreads();

    const size_t obase = ((size_t)(bt * N_ + n0)) * N_ + tid;
    #pragma unroll
    for (int nn = 0; nn < CHUNK; ++nn)
        out[obase + (size_t)nn * N_] = pbuf[nn][tid] * fast_rcp(totL[nn]);
}

extern "C" void kernel_launch(void* const* d_in, const int* in_sizes, int n_in,
                              void* d_out, int out_size, void* d_ws, size_t ws_size,
                              hipStream_t stream) {
    const float* query = (const float*)d_in[0];
    const float* keys  = (const float*)d_in[1];
    const float* Wq    = (const float*)d_in[2];
    const float* bq    = (const float*)d_in[3];
    const float* Wk    = (const float*)d_in[4];
    const float* bk    = (const float*)d_in[5];
    const float* wt    = (const float*)d_in[6];
    float* out = (float*)d_out;

    float* StreamQ = (float*)d_ws;                         // B*N*128 floats = 512 KB
    float* EkT     = StreamQ + (size_t)B_ * N_ * 4 * NP;   // B*T*D*N floats = 2 MB
    float* hdr     = EkT + (size_t)B_ * T_ * D_ * N_;      // 1 float

    const int rows = B_ * N_ + B_ * T_ * N_;               // 9216, 4 rows/block
    hipLaunchKernelGGL(tattn_proj_kernel, dim3(rows / 4), dim3(256), 0, stream,
                       query, keys, Wq, bq, Wk, bk, wt, StreamQ, EkT, hdr);

    hipLaunchKernelGGL(tattn_main_kernel, dim3(B_ * T_ * NCH), dim3(256), 0, stream,
                       StreamQ, EkT, hdr, out);
}